// Round 8
// baseline (1246.705 us; speedup 1.0000x reference)
//
#include <hip/hip_runtime.h>

typedef unsigned int u32;
typedef unsigned short u16;
typedef unsigned long long u64;

#define NT 16384
#define LN7 1.9459101090932196f
#define ZWORDS 123136   // Tp 4096 + Tpf 4096 + hs 256 + upT 114688 u64 words

__device__ __forceinline__ u32 f2bf(float f){
  u32 u = __float_as_uint(f);
  return (u + 0x7fffu + ((u >> 16) & 1u)) >> 16;   // RNE to bf16
}
__device__ __forceinline__ float bflo(u32 v){ return __uint_as_float(v << 16); }

__global__ __launch_bounds__(1024) void k_zero(u64* p){
  int i = blockIdx.x * 1024 + threadIdx.x;
  if (i < ZWORDS) p[i] = 0ull;
}

// ---- sync primitives ----
// device scope (proven rounds 0/4/5/6/7): bypass L1+L2, coherent at MALL.
__device__ __forceinline__ void st_dev(u64* p, u64 v){
  asm volatile("global_store_dwordx2 %0, %1, off sc0 sc1" :: "v"(p), "v"(v) : "memory");
}
__device__ __forceinline__ u64 ld_dev(const u64* p){
  u64 v;
  asm volatile("global_load_dwordx2 %0, %1, off sc0 sc1\n\ts_waitcnt vmcnt(0)"
               : "=v"(v) : "v"(p) : "memory");
  return v;
}
__device__ __forceinline__ void ld2_dev(const u64* p0, const u64* p1, u64& a, u64& b){
  asm volatile("global_load_dwordx2 %0, %2, off sc0 sc1\n\t"
               "global_load_dwordx2 %1, %3, off sc0 sc1\n\t"
               "s_waitcnt vmcnt(0)"
               : "=&v"(a), "=&v"(b) : "v"(p0), "v"(p1) : "memory");
}
__device__ __forceinline__ u64 ld_issue(const u64* p){
  u64 v;
  asm volatile("global_load_dwordx2 %0, %1, off sc0 sc1" : "=v"(v) : "v"(p));
  return v;
}
// XCD-local fast path: producer sc0 store = write-THROUGH L1 into local L2;
// consumer polls via L2 atomic (sc0 = return old value) — atomics execute at
// the L2 and cannot be served by a stale L1 line (r1's failure mechanism).
__device__ __forceinline__ void st_l2(u64* p, u64 v){
  asm volatile("global_store_dwordx2 %0, %1, off sc0" :: "v"(p), "v"(v) : "memory");
}
__device__ __forceinline__ void atom2_or0(u64* p0, u64* p1, u64& a, u64& b){
  asm volatile("global_atomic_or_x2 %0, %2, %4, off sc0\n\t"
               "global_atomic_or_x2 %1, %3, %4, off sc0\n\t"
               "s_waitcnt vmcnt(0)"
               : "=&v"(a), "=&v"(b) : "v"(p0), "v"(p1), "v"(0ull) : "memory");
}

// ============================================================================
// k_pre: unchanged from round 7 (measured ~55 us, no spill).
// ============================================================================
__global__ __launch_bounds__(1024) void k_pre(
    const float* __restrict__ inp,
    const float* __restrict__ Wk, const float* __restrict__ Wv,
    const float* __restrict__ lning, const float* __restrict__ lninb,
    const float* __restrict__ wiw, const float* __restrict__ wib,
    u16* __restrict__ knb, u16* __restrict__ valb,
    float* __restrict__ lgA, float* __restrict__ rnA,
    float* __restrict__ lsePart)
{
  const int tid = threadIdx.x, blk = blockIdx.x;
  const int batch = blk >> 7, chunk = blk & 127;
  const size_t growbase = ((size_t)batch << 14) + ((size_t)chunk << 7);

  __shared__ float Xs[64*132];
  __shared__ float Ws[64*132];
  __shared__ float red[16][2];

  {
    const int r = tid >> 3, p = tid & 7, base8 = p << 3;
    const size_t row = growbase + r;
    float x8[8];
    const float4* xp = (const float4*)(inp + row*64 + base8);
    float4 a = xp[0], b = xp[1];
    x8[0]=a.x; x8[1]=a.y; x8[2]=a.z; x8[3]=a.w;
    x8[4]=b.x; x8[5]=b.y; x8[6]=b.z; x8[7]=b.w;
    float s1 = 0.f;
    #pragma unroll
    for (int i = 0; i < 8; ++i) s1 += x8[i];
    #pragma unroll
    for (int off = 1; off < 8; off <<= 1) s1 += __shfl_xor(s1, off, 64);
    const float mean = s1 * (1.f/64.f);
    float s2 = 0.f;
    #pragma unroll
    for (int i = 0; i < 8; ++i){ float d = x8[i]-mean; s2 += d*d; }
    #pragma unroll
    for (int off = 1; off < 8; off <<= 1) s2 += __shfl_xor(s2, off, 64);
    const float rstd = rsqrtf(s2*(1.f/64.f) + 1e-5f);
    float lgp = 0.f;
    #pragma unroll
    for (int i = 0; i < 8; ++i){
      float xv = (x8[i]-mean)*rstd*lning[base8+i] + lninb[base8+i];
      lgp += xv*wiw[base8+i];
      Xs[(base8+i)*132 + r] = xv;
    }
    #pragma unroll
    for (int off = 1; off < 8; off <<= 1) lgp += __shfl_xor(lgp, off, 64);
    const float lg = lgp + wib[0];
    if (p == 0) lgA[row] = lg;
    float m = (p == 0) ? lg : -3.4e38f;
    float s = (p == 0) ? 1.f : 0.f;
    #pragma unroll
    for (int off = 1; off < 64; off <<= 1){
      float om = __shfl_xor(m, off, 64);
      float os = __shfl_xor(s, off, 64);
      float nm = fmaxf(m, om);
      s = s*__expf(m-nm) + os*__expf(om-nm);
      m = nm;
    }
    if ((tid & 63) == 0){ red[tid>>6][0] = m; red[tid>>6][1] = s; }
  }
  {
    const int c = tid >> 3, k0 = (tid & 7) << 3;
    const float* src = (c < 64) ? (Wk + c*64 + k0) : (Wv + (size_t)(c-64)*64 + k0);
    float4 w0 = *(const float4*)src;
    float4 w1 = *(const float4*)(src + 4);
    Ws[(k0+0)*132 + c] = w0.x; Ws[(k0+1)*132 + c] = w0.y;
    Ws[(k0+2)*132 + c] = w0.z; Ws[(k0+3)*132 + c] = w0.w;
    Ws[(k0+4)*132 + c] = w1.x; Ws[(k0+5)*132 + c] = w1.y;
    Ws[(k0+6)*132 + c] = w1.z; Ws[(k0+7)*132 + c] = w1.w;
  }
  __syncthreads();
  if (tid == 0){
    float M = red[0][0];
    for (int w = 1; w < 16; ++w) M = fmaxf(M, red[w][0]);
    float S = 0.f;
    for (int w = 0; w < 16; ++w) S += __expf(red[w][0]-M)*red[w][1];
    lsePart[blk*2+0] = M;
    lsePart[blk*2+1] = S;
  }

  const int tr = tid >> 5, tc = tid & 31;
  float acc[4][4] = {{0.f,0.f,0.f,0.f},{0.f,0.f,0.f,0.f},
                     {0.f,0.f,0.f,0.f},{0.f,0.f,0.f,0.f}};
  #pragma unroll 4
  for (int kk = 0; kk < 64; ++kk){
    float4 a4 = *(const float4*)&Xs[kk*132 + 4*tr];
    float4 b4 = *(const float4*)&Ws[kk*132 + 4*tc];
    float av[4] = {a4.x, a4.y, a4.z, a4.w};
    float bv[4] = {b4.x, b4.y, b4.z, b4.w};
    #pragma unroll
    for (int i = 0; i < 4; ++i)
      #pragma unroll
      for (int j = 0; j < 4; ++j) acc[i][j] += av[i]*bv[j];
  }
  if (tc < 16){
    float ssq[4];
    #pragma unroll
    for (int i = 0; i < 4; ++i)
      ssq[i] = acc[i][0]*acc[i][0] + acc[i][1]*acc[i][1]
             + acc[i][2]*acc[i][2] + acc[i][3]*acc[i][3];
    #pragma unroll
    for (int off = 1; off < 16; off <<= 1)
      #pragma unroll
      for (int i = 0; i < 4; ++i) ssq[i] += __shfl_xor(ssq[i], off, 64);
    if (tc == 0){
      #pragma unroll
      for (int i = 0; i < 4; ++i)
        rnA[growbase + 4*tr + i] = 1.f/fmaxf(sqrtf(ssq[i]), 1e-12f);
    }
    #pragma unroll
    for (int i = 0; i < 4; ++i){
      u32 lo = f2bf(acc[i][0]) | (f2bf(acc[i][1]) << 16);
      u32 hi = f2bf(acc[i][2]) | (f2bf(acc[i][3]) << 16);
      *(uint2*)(knb + (growbase + 4*tr + i)*64 + 4*tc) = make_uint2(lo, hi);
    }
  } else {
    const int tcv = tc - 16;
    #pragma unroll
    for (int i = 0; i < 4; ++i){
      u32 lo = f2bf(acc[i][0]) | (f2bf(acc[i][1]) << 16);
      u32 hi = f2bf(acc[i][2]) | (f2bf(acc[i][3]) << 16);
      *(uint2*)(valb + (growbase + 4*tr + i)*64 + 4*tcv) = make_uint2(lo, hi);
    }
  }
}

// ============================================================================
// k_mesh: r7 wave-0 MESH structure + XCD-local fast sync:
// XCC_ID handshake (device scope, proven protocol shape) -> if a batch's 16
// parties share an XCD, rounds use {sc0 store -> L2} + {bounded L2-atomic
// poll}; else/fallback: proven device-scope path. Deadlock-impossible.
// ============================================================================
__global__ __launch_bounds__(1024) void k_mesh(
    const float* __restrict__ noise, const float* __restrict__ mu,
    const float* __restrict__ sigma, const float* __restrict__ Wq,
    const float* __restrict__ gwih, const float* __restrict__ gwhh,
    const float* __restrict__ gbih, const float* __restrict__ gbhh,
    const float* __restrict__ fc1w, const float* __restrict__ fc1b,
    const float* __restrict__ fc2w, const float* __restrict__ fc2b,
    const float* __restrict__ lnslg, const float* __restrict__ lnslb,
    const float* __restrict__ lnffg, const float* __restrict__ lnffb,
    const float* __restrict__ wsw, const float* __restrict__ wsb,
    const u16* __restrict__ knb, const u16* __restrict__ valb,
    const float* __restrict__ lgA, const float* __restrict__ rnA,
    const float* __restrict__ lsePart,
    u64* Tp, u64* Tpf, u64* hs, u64* upT, float* out)
{
  const int tid = threadIdx.x;
  const int blk = blockIdx.x;
  const int batch = (blk & 7) | ((blk >> 7) << 3);
  const int party = (blk >> 3) & 15;
  const int bp    = (batch << 4) | party;
  const int rbase = party << 10;

  __shared__ float Sl[7][64], Qn[7][64], Qt[7][64], Sst[7][64];
  __shared__ float Gx[7][192], Gh[7][192], H1[7][128];
  __shared__ float uacc[16][7][64];
  __shared__ float red[16][8];
  __shared__ float vhL[6][8], logb[8], evT5L[8];
  __shared__ float polW[128];
  __shared__ float ecL[1024*9];
  __shared__ float pbL[1024*9];
  __shared__ float aRL[1024];
  __shared__ float rse5L[1024];
  __shared__ float sS[2];
  __shared__ int sfast;

  float* ab = out + 7168 + (size_t)batch * 7 * NT;

  u32 bstep = 0;     // wave-0 MESH tag counter (identical across blocks)
  int tbuf = 0;
  int fastTries = 0, failcnt = 0;

  // ---- XCC_ID handshake: are this batch's 16 parties on one XCD? ----
  u32 xcc;
  asm volatile("s_getreg_b32 %0, hwreg(HW_REG_XCC_ID)" : "=s"(xcc));
  xcc &= 0xffu;
  if (tid == 0) st_dev(&hs[bp], (0xC0FFEEull << 32) | (u64)xcc);

  // ---- init: combine batch LSE (128 k_pre partials); per-row aR to LDS ----
  if (tid == 1){
    const float* lp = lsePart + batch*256;
    float M = lp[0];
    for (int w = 1; w < 128; ++w) M = fmaxf(M, lp[2*w]);
    float S = 0.f;
    for (int w = 0; w < 128; ++w) S += __expf(lp[2*w] - M) * lp[2*w + 1];
    sS[0] = M + __logf(S);
  }
  if (tid < 64){
    u64 v = 0;
    bool ok;
    const u64* src = &hs[(batch << 4) + (tid & 15)];
    do {
      if (tid < 16) v = ld_dev(src);
      ok = (tid >= 16) || ((u32)(v >> 32) == 0xC0FFEEu);
    } while (!__all(ok));
    int same = (tid >= 16) || (((u32)v & 0xffu) == xcc);
    int all16 = __all(same);
    if (tid == 0) sfast = all16;
  }
  __syncthreads();
  fastTries = (sfast != 0) ? 48 : 0;
  const float LSE = sS[0];
  const size_t gr = ((size_t)batch << 14) | (size_t)(rbase | tid);
  aRL[tid] = __expf(lgA[gr] - LSE + LN7);

  for (int it = 0; it < 3; ++it){
    // ---- prologue: slots -> sn, logb, q, qn ----
    if (tid < 448){
      float sl;
      if (it == 0){
        const int d = tid & 63;
        sl = mu[d] + (fabsf(sigma[d]) + 1e-8f) * noise[batch*448 + tid];
      } else sl = Sst[tid>>6][tid&63];
      Sl[tid>>6][tid&63] = sl;
    }
    if (tid < 8) vhL[5][tid] = 0.f;
    __syncthreads();
    if (tid < 7){
      float m2 = 0.f;
      for (int d = 0; d < 64; ++d) m2 += Sl[tid][d];
      m2 *= (1.f/64.f);
      float v2 = 0.f;
      for (int d = 0; d < 64; ++d){ float dd = Sl[tid][d]-m2; v2 += dd*dd; }
      v2 *= (1.f/64.f);
      float rs2 = rsqrtf(v2 + 1e-5f);
      float lgq = wsb[0];
      for (int d = 0; d < 64; ++d){
        float s = (Sl[tid][d]-m2)*rs2*lnslg[d] + lnslb[d];
        Qt[tid][d] = s;
        lgq += s*wsw[d];
      }
      red[0][tid] = lgq;
    }
    __syncthreads();
    if (tid == 0){
      float mx = red[0][0];
      for (int s = 1; s < 7; ++s) mx = fmaxf(mx, red[0][s]);
      float sm = 0.f;
      for (int s = 0; s < 7; ++s) sm += __expf(red[0][s]-mx);
      float lse = mx + __logf(sm);
      for (int s = 0; s < 7; ++s) logb[s] = red[0][s] - lse + LN7;
    }
    __syncthreads();
    if (tid < 448){
      const int s = tid >> 6, d = tid & 63;
      const float* wr = Wq + d*64;
      float acc2 = 0.f;
      #pragma unroll
      for (int dd = 0; dd < 64; ++dd) acc2 += Qt[s][dd]*wr[dd];
      Sl[s][d] = acc2;
    }
    __syncthreads();
    if (tid < 7){
      float sq = 0.f;
      for (int d = 0; d < 64; ++d) sq += Sl[tid][d]*Sl[tid][d];
      red[1][tid] = 1.f/fmaxf(sqrtf(sq), 1e-12f);
    }
    __syncthreads();
    if (tid < 448) Qn[tid>>6][tid&63] = Sl[tid>>6][tid&63]*red[1][tid>>6];
    __syncthreads();

    // ---- C build -> ecL[tid][s] = exp(-c) ----
    {
      float acc[7] = {0.f,0.f,0.f,0.f,0.f,0.f,0.f};
      const uint4* kr = (const uint4*)(knb + gr*64);
      #pragma unroll
      for (int q8 = 0; q8 < 8; ++q8){
        uint4 kv = kr[q8];
        float f0=bflo(kv.x), f1=__uint_as_float(kv.x & 0xffff0000u);
        float f2=bflo(kv.y), f3=__uint_as_float(kv.y & 0xffff0000u);
        float f4=bflo(kv.z), f5=__uint_as_float(kv.z & 0xffff0000u);
        float f6=bflo(kv.w), f7=__uint_as_float(kv.w & 0xffff0000u);
        const int d0 = q8*8;
        #pragma unroll
        for (int s = 0; s < 7; ++s){
          const float4 qa = *(const float4*)&Qn[s][d0];
          const float4 qb = *(const float4*)&Qn[s][d0+4];
          acc[s] += f0*qa.x + f1*qa.y + f2*qa.z + f3*qa.w
                  + f4*qb.x + f5*qb.y + f6*qb.z + f7*qb.w;
        }
      }
      const float rn_ = rnA[gr];
      #pragma unroll
      for (int s = 0; s < 7; ++s)
        ecL[tid*9+s] = __expf(-(1.f - rn_*acc[s]));
    }
    __syncthreads();

    // ================= WAVE-0 MESH (no intra-block barriers) =================
    if (tid < 64){
      const int lane = tid;
      float logb7[7];
      #pragma unroll
      for (int s = 0; s < 7; ++s) logb7[s] = logb[s];

      auto sync7 = [&](float (&part)[7], float (&T7)[7]){
        #pragma unroll
        for (int off = 32; off > 0; off >>= 1)
          #pragma unroll
          for (int s = 0; s < 7; ++s) part[s] += __shfl_xor(part[s], off, 64);
        ++bstep;
        float pv = part[0];
        pv = (lane==1)?part[1]:pv; pv = (lane==2)?part[2]:pv;
        pv = (lane==3)?part[3]:pv; pv = (lane==4)?part[4]:pv;
        pv = (lane==5)?part[5]:pv; pv = (lane==6)?part[6]:pv;
        if (lane < 7){
          u64 word = ((u64)bstep << 32) | (u64)__float_as_uint(pv);
          st_l2 (&Tpf[(tbuf<<11) + bp*8 + lane], word);
          st_dev(&Tp [(tbuf<<11) + bp*8 + lane], word);
        }
        u64* baseF = &Tpf[(tbuf<<11) + (size_t)(batch << 4)*8];
        const u64* baseD = &Tp[(tbuf<<11) + (size_t)(batch << 4)*8];
        const bool isPad = ((lane & 7) == 7);
        u64 v0, v1; bool got = false;
        for (int k = 0; k < fastTries; ++k){
          atom2_or0(baseF + lane, baseF + 64 + lane, v0, v1);
          bool ok = isPad || (((u32)(v0>>32) == bstep) && ((u32)(v1>>32) == bstep));
          if (__all(ok)){ got = true; break; }
        }
        if (!got){
          bool ok;
          do {
            ld2_dev(baseD + lane, baseD + 64 + lane, v0, v1);
            ok = isPad || (((u32)(v0>>32) == bstep) && ((u32)(v1>>32) == bstep));
          } while (!__all(ok));
          if (fastTries){ if (++failcnt >= 2) fastTries = 0; }
        }
        polW[lane]      = __uint_as_float((u32)v0);
        polW[64 + lane] = __uint_as_float((u32)v1);
        #pragma unroll
        for (int s = 0; s < 7; ++s){
          float T = 0.f;
          #pragma unroll
          for (int w = 0; w < 16; ++w) T += polW[w*8+s];
          T7[s] = T;
        }
        tbuf ^= 1;
      };

      float ev[7], vwv[7], rtv[7];
      #pragma unroll 1
      for (int m = 0; m < 5; ++m){
        float mxp[6];
        {
          float v5[7];
          #pragma unroll
          for (int s = 0; s < 7; ++s) v5[s] = vhL[5][s];
          float mxn = v5[0];
          #pragma unroll
          for (int s = 1; s < 7; ++s) mxn = fmaxf(mxn, v5[s]);
          if (lane == 0){
            #pragma unroll
            for (int s = 0; s < 7; ++s) vhL[0][s] = v5[s];
          }
          mxp[1] = mxn;
          #pragma unroll
          for (int s = 0; s < 7; ++s) ev[s] = __expf(v5[s] - mxn);
        }
        // ---- fwd t=1..5 ----
        #pragma unroll
        for (int t = 1; t <= 5; ++t){
          float t7[7] = {0.f,0.f,0.f,0.f,0.f,0.f,0.f};
          #pragma unroll 2
          for (int rr = 0; rr < 16; ++rr){
            const int row = (rr << 6) | lane;
            float e[7];
            #pragma unroll
            for (int s = 0; s < 7; ++s) e[s] = ecL[row*9+s];
            const float aRr = aRL[row];
            float se = e[0]*ev[0];
            #pragma unroll
            for (int s = 1; s < 7; ++s) se += e[s]*ev[s];
            const float rse = 1.f/se;
            if (t == 5) rse5L[row] = rse;
            const float w = aRr*rse;
            #pragma unroll
            for (int s = 0; s < 7; ++s) t7[s] += w*e[s];
          }
          float T7[7];
          sync7(t7, T7);
          float vht[7];
          #pragma unroll
          for (int s = 0; s < 7; ++s) vht[s] = logb7[s] + mxp[t] - __logf(T7[s]);
          if (lane == 0){
            #pragma unroll
            for (int s = 0; s < 7; ++s) vhL[t][s] = vht[s];
          }
          if (t < 5){
            float mxn = vht[0];
            #pragma unroll
            for (int s = 1; s < 7; ++s) mxn = fmaxf(mxn, vht[s]);
            mxp[t+1] = mxn;
            #pragma unroll
            for (int s = 0; s < 7; ++s) ev[s] = __expf(vht[s] - mxn);
          } else {
            #pragma unroll
            for (int s = 0; s < 7; ++s) ev[s] = __expf(vht[s] - mxp[5]);
          }
        }
        if (m == 4) break;
        // ---- G phase ----
        {
          float vh5r[7];
          #pragma unroll
          for (int s = 0; s < 7; ++s) vh5r[s] = vhL[5][s];
          const float mx5 = mxp[5];
          float gs[7] = {0.f,0.f,0.f,0.f,0.f,0.f,0.f};
          #pragma unroll 2
          for (int rr = 0; rr < 16; ++rr){
            const int row = (rr << 6) | lane;
            float e[7];
            #pragma unroll
            for (int s = 0; s < 7; ++s) e[s] = ecL[row*9+s];
            const float aRr = aRL[row];
            const float r5 = rse5L[row];
            const float q = aRr*r5;
            const float basel = __logf(aRr) - mx5 + __logf(r5);
            #pragma unroll
            for (int s = 0; s < 7; ++s){
              float at = q * e[s] * ev[s];
              float lat = basel + vh5r[s] + __logf(e[s]);
              float G = -at * (lat + 1.f);
              pbL[row*9+s] = G;
              gs[s] += G;
            }
          }
          float T7[7];
          sync7(gs, T7);
          #pragma unroll
          for (int s = 0; s < 7; ++s){
            vwv[s] = T7[s] * __expf(vh5r[s] - logb7[s] - mxp[5]);
            rtv[s] = __expf(vhL[4][s] - mxp[5]);
          }
        }
        // ---- backward t=5..1 ----
        #pragma unroll
        for (int t = 5; t >= 1; --t){
          float evt[7];
          #pragma unroll
          for (int s = 0; s < 7; ++s) evt[s] = __expf(vhL[t-1][s] - mxp[t]);
          float ra[7] = {0.f,0.f,0.f,0.f,0.f,0.f,0.f};
          #pragma unroll 2
          for (int rr = 0; rr < 16; ++rr){
            const int row = (rr << 6) | lane;
            float e[7], pb[7];
            #pragma unroll
            for (int s = 0; s < 7; ++s) e[s] = ecL[row*9+s];
            #pragma unroll
            for (int s = 0; s < 7; ++s) pb[s] = pbL[row*9+s];
            const float aRr = aRL[row];
            float se = e[0]*evt[0];
            #pragma unroll
            for (int s = 1; s < 7; ++s) se += e[s]*evt[s];
            const float rse = 1.f/se;
            float ub = 0.f;
            if (t == 5){
              #pragma unroll
              for (int s = 0; s < 7; ++s) ub += pb[s];
            }
            float s1 = e[0]*vwv[0];
            #pragma unroll
            for (int s = 1; s < 7; ++s) s1 += e[s]*vwv[s];
            ub -= aRr * rse * s1;
            const float u2 = ub * rse;
            const float ar_ = aRr * rse;
            #pragma unroll
            for (int s = 0; s < 7; ++s){
              float er = e[s] * rtv[s];
              ra[s] += u2 * er;
              pb[s] -= ar_ * vwv[s] * e[s] + u2 * er;
            }
            if (t > 1){
              #pragma unroll
              for (int s = 0; s < 7; ++s) pbL[row*9+s] = pb[s];
            } else {
              #pragma unroll
              for (int s = 0; s < 7; ++s) ecL[row*9+s] = e[s] * __expf(-pb[s]);
            }
          }
          if (t > 1){
            float T7[7];
            sync7(ra, T7);
            #pragma unroll
            for (int s = 0; s < 7; ++s){
              vwv[s] = -T7[s] * __expf(vhL[t-1][s] - logb7[s] - mxp[t-1]);
              rtv[s] = __expf(vhL[t-2][s] - mxp[t-1]);
            }
          }
        }
      } // m
      if (lane == 0){
        #pragma unroll
        for (int s = 0; s < 7; ++s) evT5L[s] = ev[s];
      }
    }
    __syncthreads();
    // =========================================================================

    // ---- attn write ----
    {
      const int n = rbase | tid;
      const float wq = aRL[tid] * rse5L[tid];
      #pragma unroll
      for (int s = 0; s < 7; ++s) ab[s*NT + n] = wq * ecL[tid*9+s] * evT5L[s];
    }
    __syncthreads();

    // ---- updates partial = attn^T @ val over this block's 1024 rows ----
    {
      const int w = tid >> 6, d = tid & 63;
      const int nb = rbase + (w << 6);
      float acc[7] = {0.f,0.f,0.f,0.f,0.f,0.f,0.f};
      const u16* vbp = valb + (((size_t)batch << 14) + (size_t)nb)*64 + d;
      #pragma unroll 1
      for (int i = 0; i < 64; i += 4){
        float4 a4[7];
        #pragma unroll
        for (int s = 0; s < 7; ++s) a4[s] = *(const float4*)(ab + s*NT + nb + i);
        #pragma unroll
        for (int j = 0; j < 4; ++j){
          float vv = bflo((u32)vbp[(size_t)(i+j)*64]);
          #pragma unroll
          for (int s = 0; s < 7; ++s) acc[s] += ((const float*)&a4[s])[j] * vv;
        }
      }
      #pragma unroll
      for (int s = 0; s < 7; ++s) uacc[w][s][d] = acc[s];
    }
    __syncthreads();

    // ---- cross-party sum of updates (16-party tagged sync, tag = it+1) ----
    {
      const u32 utag = (u32)(it + 1);
      if (tid < 448){
        float u_ = 0.f;
        #pragma unroll
        for (int w = 0; w < 16; ++w) u_ += uacc[w][tid >> 6][tid & 63];
        st_dev(&upT[(size_t)bp*448 + tid],
               ((u64)utag << 32) | (u64)__float_as_uint(u_));
        const u64* base = &upT[(size_t)(batch << 4)*448 + tid];
        u64 vv[16];
        bool ok;
        do{
          #pragma unroll
          for (int p = 0; p < 16; ++p) vv[p] = ld_issue(base + p*448);
          asm volatile("s_waitcnt vmcnt(0)"
            : "+v"(vv[0]),"+v"(vv[1]),"+v"(vv[2]),"+v"(vv[3]),
              "+v"(vv[4]),"+v"(vv[5]),"+v"(vv[6]),"+v"(vv[7]),
              "+v"(vv[8]),"+v"(vv[9]),"+v"(vv[10]),"+v"(vv[11]),
              "+v"(vv[12]),"+v"(vv[13]),"+v"(vv[14]),"+v"(vv[15])
            :: "memory");
          ok = true;
          #pragma unroll
          for (int p = 0; p < 16; ++p) ok = ok && ((u32)(vv[p] >> 32) == utag);
        } while (!__all(ok));
        float u_t = 0.f;
        #pragma unroll
        for (int p = 0; p < 16; ++p) u_t += __uint_as_float((u32)vv[p]);
        Sl[tid>>6][tid&63] = u_t;                                  // updates
        float sp;
        if (it == 0){
          const int d = tid & 63;
          sp = mu[d] + (fabsf(sigma[d]) + 1e-8f) * noise[batch*448 + tid];
        } else sp = Sst[tid>>6][tid&63];
        Qt[tid>>6][tid&63] = sp;                                   // slots_prev
      }
    }
    __syncthreads();

    // ---- epilogue: GRU + LN + MLP (block-local, redundant per party) ----
    for (int o = tid; o < 2688; o += 1024){
      const int sl = o / 384, oo = o - sl*384;
      if (oo < 192){
        const float* wr = gwih + oo*64;
        float acc2 = gbih[oo];
        #pragma unroll
        for (int dd = 0; dd < 64; ++dd) acc2 += Sl[sl][dd]*wr[dd];
        Gx[sl][oo] = acc2;
      } else {
        const int o2 = oo - 192;
        const float* wr = gwhh + o2*64;
        float acc2 = gbhh[o2];
        #pragma unroll
        for (int dd = 0; dd < 64; ++dd) acc2 += Qt[sl][dd]*wr[dd];
        Gh[sl][o2] = acc2;
      }
    }
    __syncthreads();
    if (tid < 448){
      const int s = tid >> 6, d = tid & 63;
      float r = 1.f/(1.f + __expf(-(Gx[s][d] + Gh[s][d])));
      float z = 1.f/(1.f + __expf(-(Gx[s][64+d] + Gh[s][64+d])));
      float nn2 = tanhf(Gx[s][128+d] + r*Gh[s][128+d]);
      Qn[s][d] = (1.f - z)*nn2 + z*Qt[s][d];
    }
    __syncthreads();
    if (tid < 7){
      float m2 = 0.f;
      for (int d = 0; d < 64; ++d) m2 += Qn[tid][d];
      m2 *= (1.f/64.f);
      float v2 = 0.f;
      for (int d = 0; d < 64; ++d){ float dd = Qn[tid][d]-m2; v2 += dd*dd; }
      v2 *= (1.f/64.f);
      float rs2 = rsqrtf(v2 + 1e-5f);
      for (int d = 0; d < 64; ++d)
        Sl[tid][d] = (Qn[tid][d]-m2)*rs2*lnffg[d] + lnffb[d];
    }
    __syncthreads();
    if (tid < 896){
      const int s = tid >> 7, h = tid & 127;
      const float* f1 = fc1w + h*64;
      float acc2 = fc1b[h];
      #pragma unroll
      for (int d = 0; d < 64; ++d) acc2 += Sl[s][d]*f1[d];
      H1[s][h] = fmaxf(acc2, 0.f);
    }
    __syncthreads();
    if (tid < 448){
      const int s = tid >> 6, d = tid & 63;
      const float* f2 = fc2w + d*128;
      float o2 = fc2b[d];
      #pragma unroll
      for (int h = 0; h < 128; ++h) o2 += H1[s][h]*f2[h];
      float res = Qn[s][d] + o2;
      Sst[s][d] = res;
      if (it == 2 && party == 0) out[batch*448 + tid] = res;
    }
    __syncthreads();
  }
}

extern "C" void kernel_launch(void* const* d_in, const int* in_sizes, int n_in,
                              void* d_out, int out_size, void* d_ws, size_t ws_size,
                              hipStream_t stream)
{
  const float* inp   = (const float*)d_in[0];
  const float* noise = (const float*)d_in[1];
  const float* mu    = (const float*)d_in[2];
  const float* sigma = (const float*)d_in[3];
  const float* Wq    = (const float*)d_in[4];
  const float* Wk    = (const float*)d_in[5];
  const float* Wv    = (const float*)d_in[6];
  const float* gwih  = (const float*)d_in[7];
  const float* gwhh  = (const float*)d_in[8];
  const float* gbih  = (const float*)d_in[9];
  const float* gbhh  = (const float*)d_in[10];
  const float* fc1w  = (const float*)d_in[11];
  const float* fc1b  = (const float*)d_in[12];
  const float* fc2w  = (const float*)d_in[13];
  const float* fc2b  = (const float*)d_in[14];
  const float* lning = (const float*)d_in[15];
  const float* lninb = (const float*)d_in[16];
  const float* lnslg = (const float*)d_in[17];
  const float* lnslb = (const float*)d_in[18];
  const float* lnffg = (const float*)d_in[19];
  const float* lnffb = (const float*)d_in[20];
  const float* wiw   = (const float*)d_in[21];
  const float* wib   = (const float*)d_in[22];
  const float* wsw   = (const float*)d_in[23];
  const float* wsb   = (const float*)d_in[24];

  char* w = (char*)d_ws;
  u16*   knb     = (u16*)(w);                     // 33,554,432 B
  u16*   valb    = (u16*)(w + 33554432);          // 33,554,432 B
  float* lgA     = (float*)(w + 67108864);        // 1,048,576 B
  float* rnA     = (float*)(w + 68157440);        // 1,048,576 B
  float* lsePart = (float*)(w + 69206016);        // 16,384 B
  u64*   Tp      = (u64*)(w + 69222400);          // 32,768 B
  u64*   Tpf     = (u64*)(w + 69255168);          // 32,768 B
  u64*   hs      = (u64*)(w + 69287936);          // 2,048 B
  u64*   upT     = (u64*)(w + 69289984);          // 917,504 B
  // total ws usage ~= 70.2 MB

  k_zero<<<121, 1024, 0, stream>>>(Tp);
  k_pre<<<2048, 1024, 0, stream>>>(inp, Wk, Wv, lning, lninb, wiw, wib,
                                   knb, valb, lgA, rnA, lsePart);
  k_mesh<<<256, 1024, 0, stream>>>(noise, mu, sigma, Wq,
                                   gwih, gwhh, gbih, gbhh,
                                   fc1w, fc1b, fc2w, fc2b,
                                   lnslg, lnslb, lnffg, lnffb, wsw, wsb,
                                   knb, valb, lgA, rnA, lsePart,
                                   Tp, Tpf, hs, upT, (float*)d_out);
  (void)in_sizes; (void)n_in; (void)out_size; (void)ws_size;
}